// Round 1
// baseline (342.779 us; speedup 1.0000x reference)
//
#include <hip/hip_runtime.h>

#define BATCH      65536
#define NUM_NODES  1110
#define GROUP      10

__global__ void zero_out_kernel(float* out) {
    out[0] = 0.0f;
}

__global__ __launch_bounds__(256) void hsm_loss_kernel(
        const float* __restrict__ x,      // [BATCH, NUM_NODES]
        const float* __restrict__ w,      // [1, NUM_NODES]
        const int*   __restrict__ target, // [BATCH]
        float* __restrict__ out)          // [1]
{
    const int b = blockIdx.x * blockDim.x + threadIdx.x;
    float acc = 0.0f;

    if (b < BATCH) {
        const int leaf = target[b];
        const float* __restrict__ row = x + (size_t)b * NUM_NODES;

        // path nodes
        const int n0 = leaf / 100;
        const int n1 = 10 + leaf / 10;
        const int n2 = 110 + leaf;
        // group starts (each group = 10 contiguous nodes)
        const int g0 = 0;
        const int g1 = 10 + (leaf / 100) * 10;
        const int g2 = 110 + (leaf / 10) * 10;

        float loss = 0.0f;

        // ---- helper expanded manually for the 3 (group, node) pairs ----
        {
            const int gs[3]  = { g0, g1, g2 };
            const int nd[3]  = { n0, n1, n2 };
            #pragma unroll
            for (int lvl = 0; lvl < 3; ++lvl) {
                const int gstart = gs[lvl];
                const int idx    = nd[lvl] - gstart;   // position of path node in its group, [0,10)
                float v[GROUP];
                #pragma unroll
                for (int i = 0; i < GROUP; ++i) v[i] = row[gstart + i];

                float m = v[0];
                #pragma unroll
                for (int i = 1; i < GROUP; ++i) m = fmaxf(m, v[i]);

                float s = 0.0f;
                float xn = v[0];
                #pragma unroll
                for (int i = 0; i < GROUP; ++i) {
                    s += __expf(v[i] - m);
                    if (i == idx) xn = v[i];
                }
                const float lp = xn - m - __logf(s);
                loss += w[nd[lvl]] * lp;
            }
        }

        acc = -loss * (1.0f / (float)BATCH);
    }

    // wave(64)-level reduction, then one atomic per wave
    #pragma unroll
    for (int off = 32; off > 0; off >>= 1)
        acc += __shfl_down(acc, off, 64);

    if ((threadIdx.x & 63) == 0)
        atomicAdd(out, acc);
}

extern "C" void kernel_launch(void* const* d_in, const int* in_sizes, int n_in,
                              void* d_out, int out_size, void* d_ws, size_t ws_size,
                              hipStream_t stream) {
    const float* x      = (const float*)d_in[0];  // inputs  [BATCH, NUM_NODES]
    const float* w      = (const float*)d_in[1];  // weights [1, NUM_NODES]
    const int*   target = (const int*)  d_in[2];  // target  [BATCH]
    // d_in[3] segment_ids, d_in[4] path_indices: structure is deterministic, hardcoded.

    float* out = (float*)d_out;

    zero_out_kernel<<<1, 1, 0, stream>>>(out);

    const int block = 256;
    const int grid  = (BATCH + block - 1) / block;
    hsm_loss_kernel<<<grid, block, 0, stream>>>(x, w, target, out);
}

// Round 2
// 333.627 us; speedup vs baseline: 1.0274x; 1.0274x over previous
//
#include <hip/hip_runtime.h>

#define BATCH      65536
#define NUM_NODES  1110

__global__ void zero_out_kernel(float* out) {
    out[0] = 0.0f;
}

// BATCH = 65536 = 256 blocks * 256 threads exactly -> no bounds check needed.
__global__ __launch_bounds__(256) void hsm_loss_kernel(
        const float* __restrict__ x,      // [BATCH, NUM_NODES]
        const float* __restrict__ w,      // [1, NUM_NODES]
        const int*   __restrict__ target, // [BATCH]
        float* __restrict__ out)          // [1]
{
    const int b = blockIdx.x * blockDim.x + threadIdx.x;

    const int leaf = target[b];
    const int q100 = leaf / 100;          // level-0 ancestor index
    const int q10  = leaf / 10;

    // group starts (10 contiguous nodes each); all even -> 8B-aligned in the row
    const int gs1 = 10 + q100 * 10;
    const int gs2 = 110 + q10 * 10;
    // position of the path node inside its group
    const int idx0 = q100;
    const int idx1 = q10 - q100 * 10;     // (leaf/10) % 10
    const int idx2 = leaf - q10 * 10;     // leaf % 10

    // row base: b*1110 floats = b*4440 bytes, 8B-aligned; gstart*4 is 8B-aligned
    const float* __restrict__ row = x + (size_t)b * NUM_NODES;
    const float2* __restrict__ p0 = (const float2*)(row);
    const float2* __restrict__ p1 = (const float2*)(row + gs1);
    const float2* __restrict__ p2 = (const float2*)(row + gs2);

    // issue ALL gathers up front (independent addresses -> single vmcnt drain)
    float2 a[3][5];
    #pragma unroll
    for (int i = 0; i < 5; ++i) a[0][i] = p0[i];
    #pragma unroll
    for (int i = 0; i < 5; ++i) a[1][i] = p1[i];
    #pragma unroll
    for (int i = 0; i < 5; ++i) a[2][i] = p2[i];

    const float w0 = w[q100];
    const float w1 = w[10 + q10];
    const float w2 = w[110 + leaf];

    const int   idxs[3] = { idx0, idx1, idx2 };
    const float wts[3]  = { w0, w1, w2 };

    float loss = 0.0f;
    #pragma unroll
    for (int lvl = 0; lvl < 3; ++lvl) {
        float v[10];
        #pragma unroll
        for (int i = 0; i < 5; ++i) { v[2*i] = a[lvl][i].x; v[2*i+1] = a[lvl][i].y; }

        float m = v[0];
        #pragma unroll
        for (int i = 1; i < 10; ++i) m = fmaxf(m, v[i]);

        float s = 0.0f, xn = v[0];
        #pragma unroll
        for (int i = 0; i < 10; ++i) {
            s += __expf(v[i] - m);
            if (i == idxs[lvl]) xn = v[i];
        }
        loss += wts[lvl] * (xn - m - __logf(s));
    }

    float acc = -loss * (1.0f / (float)BATCH);

    // wave(64) shuffle reduction
    #pragma unroll
    for (int off = 32; off > 0; off >>= 1)
        acc += __shfl_down(acc, off, 64);

    // block reduction across 4 waves -> one atomic per block (256 total)
    __shared__ float sacc[4];
    const int wid = threadIdx.x >> 6;
    if ((threadIdx.x & 63) == 0) sacc[wid] = acc;
    __syncthreads();
    if (threadIdx.x == 0) {
        atomicAdd(out, sacc[0] + sacc[1] + sacc[2] + sacc[3]);
    }
}

extern "C" void kernel_launch(void* const* d_in, const int* in_sizes, int n_in,
                              void* d_out, int out_size, void* d_ws, size_t ws_size,
                              hipStream_t stream) {
    const float* x      = (const float*)d_in[0];  // inputs  [BATCH, NUM_NODES]
    const float* w      = (const float*)d_in[1];  // weights [1, NUM_NODES]
    const int*   target = (const int*)  d_in[2];  // target  [BATCH]
    // d_in[3] segment_ids, d_in[4] path_indices: deterministic structure, hardcoded.

    float* out = (float*)d_out;

    zero_out_kernel<<<1, 1, 0, stream>>>(out);

    const int block = 256;
    const int grid  = BATCH / block;   // 256
    hsm_loss_kernel<<<grid, block, 0, stream>>>(x, w, target, out);
}

// Round 3
// 329.993 us; speedup vs baseline: 1.0387x; 1.0110x over previous
//
#include <hip/hip_runtime.h>

#define BATCH      65536
#define NUM_NODES  1110
#define NUM_WAVES  (BATCH / 64)   // 1024 wave partials

// Kernel 1: per-sample hierarchical-softmax path loss, wave-reduced,
// one pure store per wave into d_ws (no atomics, no init required).
__global__ __launch_bounds__(256) void hsm_loss_kernel(
        const float* __restrict__ x,      // [BATCH, NUM_NODES]
        const float* __restrict__ w,      // [1, NUM_NODES]
        const int*   __restrict__ target, // [BATCH]
        float* __restrict__ partials)     // [NUM_WAVES]
{
    const int b = blockIdx.x * blockDim.x + threadIdx.x;

    const int leaf = target[b];
    const int q100 = leaf / 100;          // level-0 ancestor index
    const int q10  = leaf / 10;

    // group starts (10 contiguous nodes each); even -> 8B-aligned
    const int gs1 = 10 + q100 * 10;
    const int gs2 = 110 + q10 * 10;
    // position of the path node inside its group
    const int idx0 = q100;
    const int idx1 = q10 - q100 * 10;     // (leaf/10) % 10
    const int idx2 = leaf - q10 * 10;     // leaf % 10

    const float* __restrict__ row = x + (size_t)b * NUM_NODES;
    const float2* __restrict__ p0 = (const float2*)(row);
    const float2* __restrict__ p1 = (const float2*)(row + gs1);
    const float2* __restrict__ p2 = (const float2*)(row + gs2);

    // issue ALL gathers up front (independent -> single vmcnt drain)
    float2 a[3][5];
    #pragma unroll
    for (int i = 0; i < 5; ++i) a[0][i] = p0[i];
    #pragma unroll
    for (int i = 0; i < 5; ++i) a[1][i] = p1[i];
    #pragma unroll
    for (int i = 0; i < 5; ++i) a[2][i] = p2[i];

    const float w0 = w[q100];
    const float w1 = w[10 + q10];
    const float w2 = w[110 + leaf];

    const int   idxs[3] = { idx0, idx1, idx2 };
    const float wts[3]  = { w0, w1, w2 };

    float loss = 0.0f;
    #pragma unroll
    for (int lvl = 0; lvl < 3; ++lvl) {
        float v[10];
        #pragma unroll
        for (int i = 0; i < 5; ++i) { v[2*i] = a[lvl][i].x; v[2*i+1] = a[lvl][i].y; }

        float m = v[0];
        #pragma unroll
        for (int i = 1; i < 10; ++i) m = fmaxf(m, v[i]);

        float s = 0.0f, xn = v[0];
        #pragma unroll
        for (int i = 0; i < 10; ++i) {
            s += __expf(v[i] - m);
            if (i == idxs[lvl]) xn = v[i];
        }
        loss += wts[lvl] * (xn - m - __logf(s));
    }

    // wave(64) shuffle reduction of the positive loss sum
    #pragma unroll
    for (int off = 32; off > 0; off >>= 1)
        loss += __shfl_down(loss, off, 64);

    if ((threadIdx.x & 63) == 0) {
        const int waveId = (blockIdx.x * blockDim.x + threadIdx.x) >> 6;
        partials[waveId] = loss;
    }
}

// Kernel 2: reduce 1024 partials, scale, pure-store the scalar output.
__global__ __launch_bounds__(256) void reduce_kernel(
        const float* __restrict__ partials, // [NUM_WAVES]
        float* __restrict__ out)            // [1]
{
    const int t = threadIdx.x;
    const float4 v = ((const float4*)partials)[t];   // 256 threads x 4 = 1024
    float s = v.x + v.y + v.z + v.w;

    #pragma unroll
    for (int off = 32; off > 0; off >>= 1)
        s += __shfl_down(s, off, 64);

    __shared__ float sacc[4];
    if ((t & 63) == 0) sacc[t >> 6] = s;
    __syncthreads();
    if (t == 0)
        out[0] = -(sacc[0] + sacc[1] + sacc[2] + sacc[3]) * (1.0f / (float)BATCH);
}

extern "C" void kernel_launch(void* const* d_in, const int* in_sizes, int n_in,
                              void* d_out, int out_size, void* d_ws, size_t ws_size,
                              hipStream_t stream) {
    const float* x      = (const float*)d_in[0];  // inputs  [BATCH, NUM_NODES]
    const float* w      = (const float*)d_in[1];  // weights [1, NUM_NODES]
    const int*   target = (const int*)  d_in[2];  // target  [BATCH]
    // d_in[3] segment_ids, d_in[4] path_indices: deterministic structure, hardcoded.

    float* partials = (float*)d_ws;               // 1024 floats, fully overwritten
    float* out      = (float*)d_out;

    hsm_loss_kernel<<<BATCH / 256, 256, 0, stream>>>(x, w, target, partials);
    reduce_kernel<<<1, 256, 0, stream>>>(partials, out);
}